// Round 1
// 925.118 us; speedup vs baseline: 1.0359x; 1.0359x over previous
//
#include <hip/hip_runtime.h>
#include <stdint.h>

#define GMAX 4096   // problem has G=4096; LDS hist/cursor sized for this
#define NB   256    // chunks for counting sort
#define CH   64     // rows staged per LDS chunk in compute kernels

// ---------- harness symbol: zero cnt (vestigial but keeps symbol + cheap) ----------
__global__ void FCAdaINLayer_68719477052_kernel(int* __restrict__ cnt, int G) {
  int t = blockIdx.x * blockDim.x + threadIdx.x;
  int stride = gridDim.x * blockDim.x;
  for (int i = t; i < G; i += stride) cnt[i] = 0;
}

// ---------- per-chunk LDS histogram: NO global atomics ----------
__global__ __launch_bounds__(256) void k_bhist(const int* __restrict__ lat, int n, int G,
                                               int* __restrict__ hist_b) {
  __shared__ int h[GMAX];
  int b = blockIdx.x, t = threadIdx.x;
  for (int g = t; g < G; g += 256) h[g] = 0;
  __syncthreads();
  int chb = (n + NB - 1) / NB;
  int beg = b * chb, end = min(beg + chb, n);
  for (int i = beg + t; i < end; i += 256) atomicAdd(&h[lat[i]], 1);
  __syncthreads();
  for (int g = t; g < G; g += 256) hist_b[(size_t)b * G + g] = h[g];
}

// ---------- per-group prefix across chunks (in place); cnt[g] = group total ----------
__global__ void k_scanA(int* __restrict__ hist_b, int G, int* __restrict__ cnt) {
  int g = blockIdx.x * blockDim.x + threadIdx.x;
  if (g >= G) return;
  int run = 0;
  for (int b = 0; b < NB; b++) {
    int v = hist_b[(size_t)b * G + g];
    hist_b[(size_t)b * G + g] = run;  // becomes within-group chunk base
    run += v;
  }
  cnt[g] = run;
}

// ---------- single-block exclusive scan over groups ----------
__global__ void k_scanB(const int* __restrict__ cnt, int G, int* __restrict__ offs) {
  __shared__ int part[256];
  int t = threadIdx.x;
  int per = (G + 255) / 256;
  int base = t * per;
  int s = 0;
  for (int j = 0; j < per; j++) { int g = base + j; if (g < G) s += cnt[g]; }
  part[t] = s;
  __syncthreads();
  if (t == 0) {
    int run = 0;
    for (int j = 0; j < 256; j++) { int v = part[j]; part[j] = run; run += v; }
  }
  __syncthreads();
  int run = part[t];
  for (int j = 0; j < per; j++) {
    int g = base + j;
    if (g < G) { offs[g] = run; run += cnt[g]; }
  }
  if (t == 255) offs[G] = run;
}

// ---------- scatter via LDS cursors: NO global atomics ----------
__global__ __launch_bounds__(256) void k_scatter2(const int* __restrict__ lat, int n, int G,
                                                  const int* __restrict__ offs,
                                                  const int* __restrict__ hist_b,
                                                  int* __restrict__ sorted) {
  __shared__ int cur[GMAX];
  int b = blockIdx.x, t = threadIdx.x;
  for (int g = t; g < G; g += 256) cur[g] = offs[g] + hist_b[(size_t)b * G + g];
  __syncthreads();
  int chb = (n + NB - 1) / NB;
  int beg = b * chb, end = min(beg + chb, n);
  for (int i = beg + t; i < end; i += 256) {
    int g = lat[i];
    int pos = atomicAdd(&cur[g], 1);  // LDS atomic (ds_add_rtn)
    sorted[pos] = i;
  }
}

// dot of a 64-float row (16 float4 broadcast reads) with per-lane W column
__device__ __forceinline__ float dot64(const float4* __restrict__ xr,
                                       const float* wcol, float bc) {
  float h0 = bc, h1 = 0.f, h2 = 0.f, h3 = 0.f;
#pragma unroll
  for (int j = 0; j < 16; j++) {
    float4 q = xr[j];
    int k = j * 4;
    h0 = fmaf(q.x, wcol[k], h0);
    h1 = fmaf(q.y, wcol[k + 1], h1);
    h2 = fmaf(q.z, wcol[k + 2], h2);
    h3 = fmaf(q.w, wcol[k + 3], h3);
  }
  return (h0 + h2) + (h1 + h3);
}

// ---------- stats: block=group; small LDS chunks; fused mu/sig; emit scale/shift ----------
__global__ __launch_bounds__(256) void k_stats(
    const float* __restrict__ x, const int* __restrict__ sorted,
    const int* __restrict__ offs, const float* __restrict__ of,
    const float* __restrict__ Wmu, const float* __restrict__ bmu,
    const float* __restrict__ Wsig, const float* __restrict__ bsig,
    const float* __restrict__ Wfc, const float* __restrict__ bfc,
    float* __restrict__ scaleT, float* __restrict__ shiftT) {
  __shared__ float xs[CH * 64];       // 16 KB
  __shared__ float red[2][4][64];     // 2 KB
  int g = blockIdx.x;
  int beg = offs[g], end = offs[g + 1];
  int cnt = end - beg;
  if (cnt == 0) return;               // stats never read for empty groups
  int tid = threadIdx.x, lane = tid & 63, wid = tid >> 6;

  float wcol[64];
#pragma unroll
  for (int k = 0; k < 64; k++) wcol[k] = Wfc[k * 64 + lane];
  float bc = bfc[lane];

  float ssum = 0.f, ssq = 0.f;
  for (int c0 = 0; c0 < cnt; c0 += CH) {
    int rows = min(CH, cnt - c0);
    __syncthreads();  // xs reuse guard
    for (int idx = tid; idx < rows * 16; idx += 256) {
      int j = idx >> 4, e = idx & 15;
      int p = sorted[beg + c0 + j];
      reinterpret_cast<float4*>(xs)[j * 16 + e] =
          reinterpret_cast<const float4*>(x + (size_t)p * 64)[e];
    }
    __syncthreads();
    for (int j = wid; j < rows; j += 4) {
      float h = dot64(reinterpret_cast<const float4*>(xs + j * 64), wcol, bc);
      ssum += h;
      ssq = fmaf(h, h, ssq);
    }
  }
  red[0][wid][lane] = ssum;
  red[1][wid][lane] = ssq;
  __syncthreads();
  if (wid == 0) {
    float ts = 0.f, tq = 0.f;
#pragma unroll
    for (int w = 0; w < 4; w++) { ts += red[0][w][lane]; tq += red[1][w][lane]; }
    float inv = 1.0f / (float)cnt;
    float mean = ts * inv;
    float var = fmaxf(tq * inv - mean * mean, 0.f);
    float rstd = rsqrtf(var + 1e-14f);
    // fused mu/sig mini-GEMM (was k_musig)
    const float* ofr = of + (size_t)g * 128;
    float a0 = 0.f, a1 = 0.f;
    for (int k = 0; k < 128; k++) {
      float ov = ofr[k];
      a0 = fmaf(ov, Wmu[k * 64 + lane], a0);
      a1 = fmaf(ov, Wsig[k * 64 + lane], a1);
    }
    float mu = a0 + bmu[lane];
    float sig = a1 + bsig[lane];
    float sc = sig * rstd;
    scaleT[(size_t)g * 64 + lane] = sc;
    shiftT[(size_t)g * 64 + lane] = mu - mean * sc;
  }
}

// ---------- apply: streaming in ORIGINAL order; recompute h; coalesced in/out ----------
__global__ __launch_bounds__(256) void k_applyn(
    const float* __restrict__ x, const int* __restrict__ lat, int n,
    const float* __restrict__ scaleT, const float* __restrict__ shiftT,
    const float* __restrict__ Wfc, const float* __restrict__ bfc,
    float* __restrict__ out) {
  __shared__ float xs[CH * 64];  // 16 KB
  int tid = threadIdx.x, lane = tid & 63, wid = tid >> 6;
  float wcol[64];
#pragma unroll
  for (int k = 0; k < 64; k++) wcol[k] = Wfc[k * 64 + lane];
  float bc = bfc[lane];

  int nchunks = (n + CH - 1) / CH;
  for (int c = blockIdx.x; c < nchunks; c += gridDim.x) {
    int p0 = c * CH;
    int rows = min(CH, n - p0);
    __syncthreads();  // xs reuse guard
    for (int idx = tid; idx < rows * 16; idx += 256) {
      reinterpret_cast<float4*>(xs)[idx] =
          reinterpret_cast<const float4*>(x + (size_t)p0 * 64)[idx];
    }
    __syncthreads();
    for (int j = wid; j < rows; j += 4) {
      int p = p0 + j;
      int g = lat[p];  // wave-uniform -> scalar load
      float h = dot64(reinterpret_cast<const float4*>(xs + j * 64), wcol, bc);
      float sc = scaleT[(size_t)g * 64 + lane];
      float sh = shiftT[(size_t)g * 64 + lane];
      out[(size_t)p * 64 + lane] = fmaxf(fmaf(h, sc, sh), 0.f);
    }
  }
}

extern "C" void kernel_launch(void* const* d_in, const int* in_sizes, int n_in,
                              void* d_out, int out_size, void* d_ws, size_t ws_size,
                              hipStream_t stream) {
  const float* x   = (const float*)d_in[0];   // [N,64] fp32
  const float* of  = (const float*)d_in[1];   // [G,128] fp32
  const int* lat   = (const int*)d_in[2];     // [N] int32
  const float* Wfc = (const float*)d_in[4];   // [64,64]
  const float* bfc = (const float*)d_in[5];   // [64]
  const float* Wmu = (const float*)d_in[6];   // [128,64]
  const float* bmu = (const float*)d_in[7];   // [64]
  const float* Wsg = (const float*)d_in[8];   // [128,64]
  const float* bsg = (const float*)d_in[9];   // [64]

  int N = in_sizes[2];
  int G = in_sizes[1] / 128;

  char* ws = (char*)d_ws;
  size_t o = 0;
  int* cnt     = (int*)(ws + o); o += (size_t)G * 4;
  int* offs    = (int*)(ws + o); o += (size_t)(G + 1) * 4;
  o = (o + 255) & ~(size_t)255;
  int* hist_b  = (int*)(ws + o); o += (size_t)NB * G * 4;     // 4 MB
  int* sorted  = (int*)(ws + o); o += (size_t)N * 4;          // 4 MB
  float* scT   = (float*)(ws + o); o += (size_t)G * 64 * 4;   // 1 MB
  float* shT   = (float*)(ws + o); o += (size_t)G * 64 * 4;   // 1 MB  (~10.1 MB total)

  FCAdaINLayer_68719477052_kernel<<<32, 256, 0, stream>>>(cnt, G);
  k_bhist<<<NB, 256, 0, stream>>>(lat, N, G, hist_b);
  k_scanA<<<(G + 255) / 256, 256, 0, stream>>>(hist_b, G, cnt);
  k_scanB<<<1, 256, 0, stream>>>(cnt, G, offs);
  k_scatter2<<<NB, 256, 0, stream>>>(lat, N, G, offs, hist_b, sorted);
  k_stats<<<G, 256, 0, stream>>>(x, sorted, offs, of, Wmu, bmu, Wsg, bsg, Wfc, bfc, scT, shT);
  k_applyn<<<2048, 256, 0, stream>>>(x, lat, N, scT, shT, Wfc, bfc, (float*)d_out);
}